// Round 17
// baseline (215.235 us; speedup 1.0000x reference)
//
#include <hip/hip_runtime.h>
#include <hip/hip_bf16.h>
#include <math.h>

#define NS   1024
#define LP   27
#define MMH  34
#define EE   16
#define LO   21
#define CT   640
#define H1   512
#define H2   256
#define LPAD 40
#define GROW (LP*LPAD)      // 1080 bf16 els per sample
#define SLOTROWS (NS*LO)    // 21504
#define ALLROWS  (3*SLOTROWS)

typedef __attribute__((ext_vector_type(8))) short  s8v;
typedef __attribute__((ext_vector_type(4))) float  f4v;

// packed conv-weight geometry: col = k*40 + m, Kcp = K*40 padded to mult-32
#define PK2_SLOT 147456     // 128*128 + 256*224 + 256*288
#define PK2_J0   0
#define PK2_J1   16384
#define PK2_J2   73728
// MLP pack offsets
#define WMLP_FAM 458752     // 512*640 + 256*512
#define WMLP_B   327680     // 512*640
#define BMLP_FAM 768
#define BMLP_B   512

__device__ __forceinline__ ushort f2b(float v) {
    __hip_bfloat16 hb = __float2bfloat16(v);
    return *reinterpret_cast<ushort*>(&hb);
}

__device__ __forceinline__ float pe_val(int pos, int e) {
    int j = e >> 1;
    float div = expf(-1.1512925464970229f * (float)j);  // 10000^(-j/8)
    float ang = (float)pos * div;
    return (e & 1) ? cosf(ang) : sinf(ang);
}

// async global->LDS 16B: LDS dest = wave-uniform base + lane*16; global src per-lane
__device__ __forceinline__ void gl16(const ushort* g, ushort* l) {
    __builtin_amdgcn_global_load_lds(
        (const __attribute__((address_space(1))) void*)g,
        (__attribute__((address_space(3))) void*)l, 16, 0, 0);
}

// XCD-aware bijective swizzle of the flat workgroup id (T1; requires nwg%8==0)
__device__ __forceinline__ int xcd_swz() {
    int fid = blockIdx.y * gridDim.x + blockIdx.x;
    int nwg = gridDim.x * gridDim.y;
    int cpx = nwg >> 3;
    return (fid & 7) * cpx + (fid >> 3);
}

// ---------------- fused prep: embG | conv pack | mlp pack | pool zero ----------------
struct PrepArgs {
    const int* pep_x; const int* mhc_x;
    const float* emb_pep; const float* emb_mhc;
    const float* cw[2][3]; const float* cb[2][3]; const float* cg[2][3]; const float* cbe[2][3];
    const float* mw[4]; const float* mb[4]; const float* mg[4]; const float* mbe[4];
    ushort* Gb; ushort* Wpack; float* bpack; ushort* Wmlp; float* bmlp; int* poolI;
};

__global__ __launch_bounds__(256) void k_prep(PrepArgs A) {
    int b = blockIdx.x, t = threadIdx.x;
    float rs = rsqrtf(1.0f + 1e-5f);
    if (b < NS) {
        __shared__ float ps[LP * 17];
        __shared__ float ms[MMH * 17];
        int n = b;
        for (int idx = t; idx < LP * EE; idx += 256) {
            int l = idx >> 4, e = idx & 15;
            float v = A.emb_pep[A.pep_x[n * LP + l] * EE + e];
            if (l >= 3 && l < 24) v += pe_val(l - 3, e);
            ps[l * 17 + e] = v;
        }
        for (int idx = t; idx < MMH * EE; idx += 256) {
            int m = idx >> 4, e = idx & 15;
            ms[m * 17 + e] = A.emb_mhc[A.mhc_x[n * MMH + m] * EE + e] + pe_val(m, e);
        }
        __syncthreads();
        for (int idx = t; idx < GROW; idx += 256) {
            int l = idx / LPAD, m = idx - l * LPAD;
            float s = 0.f;
            if (m < MMH) {
                #pragma unroll
                for (int e = 0; e < EE; ++e) s = fmaf(ps[l * 17 + e], ms[m * 17 + e], s);
            }
            A.Gb[(size_t)n * GROW + idx] = f2b(s);
        }
        if (n == 0 && t < 64) A.Gb[(size_t)NS * GROW + t] = 0;
    } else if (b < NS + 144) {
        const int KS_[3]  = {3, 5, 7};
        const int KCP_[3] = {128, 224, 288};
        const int NC_[3]  = {128, 256, 256};
        const int pkoff[3] = {PK2_J0, PK2_J1, PK2_J2};
        const int bpoff[3] = {0, 128, 384};
        int lin = b - NS;
        int s = lin / 48, rem = lin - s * 48, j = rem >> 4, z = rem & 15;
        int K = KS_[j], Kcp = KCP_[j], nc = NC_[j];
        int fam = (s == 0) ? 0 : 1;
        const float* w  = A.cw[fam][j];
        const float* g  = A.cg[fam][j];
        ushort* Wp = A.Wpack + s * PK2_SLOT + pkoff[j];
        int tot = nc * Kcp;
        for (int idx = z * 256 + t; idx < tot; idx += 16 * 256) {
            int c = idx / Kcp, col = idx - c * Kcp;
            int k = col / LPAD, m = col - k * LPAD;
            float v = 0.f;
            if (k < K && m < MMH) {
                int kk = (s == 2) ? (K - 1 - k) : k;
                v = w[((size_t)c * K + kk) * MMH + m] * (g[c] * rs);
            }
            Wp[idx] = f2b(v);
        }
        if (z == 0) {
            const float* bb = A.cb[fam][j];
            const float* be = A.cbe[fam][j];
            float* bp = A.bpack + s * CT + bpoff[j];
            for (int c = t; c < nc; c += 256)
                bp[c] = bb[c] * (g[c] * rs) + be[c];
        }
    } else if (b < NS + 144 + 112) {
        int lin = b - NS - 144;
        int task, rel, nb;
        if (lin < 40)      { task = 0; rel = lin;      nb = 40; }
        else if (lin < 56) { task = 1; rel = lin - 40; nb = 16; }
        else if (lin < 96) { task = 2; rel = lin - 56; nb = 40; }
        else               { task = 3; rel = lin - 96; nb = 16; }
        int fam = task >> 1, stage = task & 1;
        int Co = stage ? H2 : H1;
        int Ci = stage ? H1 : CT;
        const float* w  = A.mw[task];
        const float* g  = A.mg[task];
        ushort* Wb = A.Wmlp + fam * WMLP_FAM + stage * WMLP_B;
        int tot = Co * Ci;
        for (int idx = rel * 256 + t; idx < tot; idx += nb * 256) {
            int o = idx / Ci;
            Wb[idx] = f2b(w[idx] * (g[o] * rs));
        }
        if (rel == 0) {
            const float* bb = A.mb[task];
            const float* be = A.mbe[task];
            float* bp = A.bmlp + fam * BMLP_FAM + stage * BMLP_B;
            for (int o = t; o < Co; o += 256)
                bp[o] = bb[o] * (g[o] * rs) + be[o];
        }
    } else {
        int base = (b - NS - 144 - 112) * 8192;
        #pragma unroll
        for (int q = 0; q < 32; ++q)
            A.poolI[base + q * 256 + t] = 0;
    }
}

// ---------------- conv as bf16 MFMA GEMM, gload_lds dbuf + counted vmcnt ----------------
__global__ __launch_bounds__(512) void k_cmfma(
    const ushort* __restrict__ Gb, const ushort* __restrict__ Wpack,
    const float* __restrict__ bpack, ushort* __restrict__ Xb, int rowBase)
{
    const int kcpm[5] = {128, 224, 224, 288, 288};
    const int offm[5] = {2, 1, 1, 0, 0};
    const int o0m[5]  = {0, 0, 128, 0, 128};
    const int c0m[5]  = {0, 128, 128, 384, 384};
    const int wofm[5] = {PK2_J0, PK2_J1, PK2_J1, PK2_J2, PK2_J2};

    __shared__ ushort smC[17408];   // buf0 [0,8192) buf1 [8192,16384) ush; epi 17408 aliased
    int wg = xcd_swz();
    int y = wg % 5, rtile = wg / 5;
    int Kcp = kcpm[y], off = offm[y], o0 = o0m[y];
    int c0X = c0m[y] + o0;
    int r0g = rowBase + rtile * 128;
    int slot = r0g / SLOTROWS;
    const ushort* Wt = Wpack + slot * PK2_SLOT + wofm[y] + (size_t)o0 * Kcp;
    const float*  bp = bpack + slot * CT;
    int p0 = rtile * 128;

    int t = threadIdx.x, lane = t & 63, wv = t >> 6;
    int r0 = (wv >> 1) * 32, c0w = (wv & 1) * 64;

    // staging descriptors: 2 chunks per wave; waves 0-3 stage A(kb=wv), 4-7 stage B(kb=wv-4)
    const ushort* sb0; const ushort* sb1; int lo0, lo1;
    {
        int isB = wv >= 4;
        int kb  = isB ? (wv - 4) : wv;
        #pragma unroll
        for (int i = 0; i < 2; ++i) {
            int hf = i, row = hf * 64 + lane;
            const ushort* s;
            if (isB) {
                s = Wt + (size_t)row * Kcp + kb * 8;
            } else {
                int rg = r0g + row;
                int rr = rg - slot * SLOTROWS;
                s = Gb + (size_t)(rr / LO) * GROW + (off + rr % LO) * LPAD + kb * 8;
            }
            int lo = (isB ? 4096 : 0) + kb * 1024 + hf * 512;
            if (i == 0) { sb0 = s; lo0 = lo; } else { sb1 = s; lo1 = lo; }
        }
    }

    f4v acc[2][4];
    #pragma unroll
    for (int m = 0; m < 2; ++m)
        #pragma unroll
        for (int n = 0; n < 4; ++n)
            acc[m][n] = (f4v){0.f, 0.f, 0.f, 0.f};

    int nkt = Kcp >> 5;
    gl16(sb0, &smC[lo0]);
    gl16(sb1, &smC[lo1]);
    for (int kt = 0; kt < nkt; ++kt) {
        if (kt + 1 < nkt) {
            int nb = ((kt + 1) & 1) << 13;
            int ko = (kt + 1) * 32;
            gl16(sb0 + ko, &smC[nb + lo0]);
            gl16(sb1 + ko, &smC[nb + lo1]);
            asm volatile("s_waitcnt vmcnt(2)" ::: "memory");
        } else {
            asm volatile("s_waitcnt vmcnt(0)" ::: "memory");
        }
        __builtin_amdgcn_sched_barrier(0);
        __builtin_amdgcn_s_barrier();
        __builtin_amdgcn_sched_barrier(0);
        int cb = (kt & 1) << 13;
        int kq = (lane >> 4) * 128;
        s8v a[2], b[4];
        #pragma unroll
        for (int m = 0; m < 2; ++m)
            a[m] = *(const s8v*)&smC[cb + (kq + r0 + m * 16 + (lane & 15)) * 8];
        #pragma unroll
        for (int n = 0; n < 4; ++n)
            b[n] = *(const s8v*)&smC[cb + 4096 + (kq + c0w + n * 16 + (lane & 15)) * 8];
        #pragma unroll
        for (int m = 0; m < 2; ++m)
            #pragma unroll
            for (int n = 0; n < 4; ++n)
                acc[m][n] = __builtin_amdgcn_mfma_f32_16x16x32_bf16(a[m], b[n], acc[m][n], 0, 0, 0);
        __builtin_amdgcn_sched_barrier(0);
        __builtin_amdgcn_s_barrier();
    }

    int cl = lane & 15, rq = lane >> 4;
    #pragma unroll
    for (int m = 0; m < 2; ++m)
        #pragma unroll
        for (int n = 0; n < 4; ++n) {
            int ocr = c0w + n * 16 + cl;
            float bv = bp[c0X + ocr];
            #pragma unroll
            for (int j = 0; j < 4; ++j)
                smC[(r0 + m * 16 + rq * 4 + j) * 136 + ocr] = f2b(fmaxf(acc[m][n][j] + bv, 0.f));
        }
    __syncthreads();
    int ci = t & 15;
    #pragma unroll
    for (int it = 0; it < 4; ++it) {
        int row = (t >> 4) + it * 32;
        *(s8v*)&Xb[(size_t)(p0 + row) * CT + c0X + ci * 8] = *(const s8v*)&smC[row * 136 + ci * 8];
    }
}

// ---------------- MLP stage A: BK=64, gload_lds dbuf + counted vmcnt ----------------
__global__ __launch_bounds__(512) void k_mgemmA(
    const ushort* __restrict__ Xin,
    const ushort* __restrict__ Wbase, const float* __restrict__ bbase,
    ushort* __restrict__ Yb, int rowBase)
{
    __shared__ ushort smA[32768];   // buf0 A[0,8192) B[8192,16384); buf1 +16384; epi 17408 aliased
    int t = threadIdx.x;
    int wg = xcd_swz();
    int o0 = (wg & 3) * 128;
    int p0 = (wg >> 2) * 128;
    int g0 = rowBase + p0;
    int fam = (g0 < SLOTROWS) ? 0 : 1;
    const ushort* Wb = Wbase + (size_t)fam * WMLP_FAM;
    const float*  bp = bbase + fam * BMLP_FAM;
    int lane = t & 63, wv = t >> 6;
    int r0 = (wv >> 1) * 32, c0 = (wv & 1) * 64;

    // staging descriptors: 4 chunks per wave (A chunks 0-15, B chunks 16-31)
    const ushort* sb[4]; int lo[4];
    #pragma unroll
    for (int i = 0; i < 4; ++i) {
        int c = wv * 4 + i;
        int isB = c >= 16;
        int cc = c & 15, kb = cc >> 1, hf = cc & 1;
        int row = hf * 64 + lane;
        sb[i] = (isB ? Wb + (size_t)(o0 + row) * CT : Xin + (size_t)(p0 + row) * CT) + kb * 8;
        lo[i] = (isB ? 8192 : 0) + kb * 1024 + hf * 512;
    }

    f4v acc[2][4];
    #pragma unroll
    for (int m = 0; m < 2; ++m)
        #pragma unroll
        for (int n = 0; n < 4; ++n)
            acc[m][n] = (f4v){0.f, 0.f, 0.f, 0.f};

    const int NKT = CT / 64;   // 10
    #pragma unroll
    for (int i = 0; i < 4; ++i) gl16(sb[i], &smA[lo[i]]);
    for (int kt = 0; kt < NKT; ++kt) {
        if (kt + 1 < NKT) {
            int nb = ((kt + 1) & 1) << 14;
            int ko = (kt + 1) * 64;
            #pragma unroll
            for (int i = 0; i < 4; ++i) gl16(sb[i] + ko, &smA[nb + lo[i]]);
            asm volatile("s_waitcnt vmcnt(4)" ::: "memory");
        } else {
            asm volatile("s_waitcnt vmcnt(0)" ::: "memory");
        }
        __builtin_amdgcn_sched_barrier(0);
        __builtin_amdgcn_s_barrier();
        __builtin_amdgcn_sched_barrier(0);
        int cb = (kt & 1) << 14;
        #pragma unroll
        for (int ks = 0; ks < 2; ++ks) {
            int kq = (ks * 4 + (lane >> 4)) * 128;
            s8v a[2], b[4];
            #pragma unroll
            for (int m = 0; m < 2; ++m)
                a[m] = *(const s8v*)&smA[cb + (kq + r0 + m * 16 + (lane & 15)) * 8];
            #pragma unroll
            for (int n = 0; n < 4; ++n)
                b[n] = *(const s8v*)&smA[cb + 8192 + (kq + c0 + n * 16 + (lane & 15)) * 8];
            #pragma unroll
            for (int m = 0; m < 2; ++m)
                #pragma unroll
                for (int n = 0; n < 4; ++n)
                    acc[m][n] = __builtin_amdgcn_mfma_f32_16x16x32_bf16(a[m], b[n], acc[m][n], 0, 0, 0);
        }
        __builtin_amdgcn_sched_barrier(0);
        __builtin_amdgcn_s_barrier();
    }

    int cl = lane & 15, rq = lane >> 4;
    #pragma unroll
    for (int m = 0; m < 2; ++m)
        #pragma unroll
        for (int n = 0; n < 4; ++n) {
            int ocr = c0 + n * 16 + cl;
            float bv = bp[o0 + ocr];
            #pragma unroll
            for (int j = 0; j < 4; ++j)
                smA[(r0 + m * 16 + rq * 4 + j) * 136 + ocr] = f2b(fmaxf(acc[m][n][j] + bv, 0.f));
        }
    __syncthreads();
    int ci = t & 15;
    #pragma unroll
    for (int it = 0; it < 4; ++it) {
        int row = (t >> 4) + it * 32;
        *(s8v*)&Yb[(size_t)(p0 + row) * H1 + o0 + ci * 8] = *(const s8v*)&smA[row * 136 + ci * 8];
    }
}

// ---------------- MLP stage B + masked max-pool: gload_lds dbuf + counted vmcnt ----------------
__global__ __launch_bounds__(512) void k_mgemmB(
    const ushort* __restrict__ Yin,
    const ushort* __restrict__ Wbase, const float* __restrict__ bbase,
    const int* __restrict__ pep_x, int* __restrict__ poolI, int rowBase)
{
    __shared__ float zbuf[16512];          // 66,048 B; staging bufs (64KB) aliased at front
    __shared__ int mvalid[128];
    ushort* smB = (ushort*)zbuf;
    int t = threadIdx.x;
    int wg = xcd_swz();
    int o0 = (wg & 1) * 128;
    int p0 = (wg >> 1) * 128;
    int g0 = rowBase + p0;
    int slot = g0 / SLOTROWS;
    int gs0 = g0 - slot * SLOTROWS;
    int fam = (slot == 0) ? 0 : 1;
    const ushort* Wb = Wbase + (size_t)fam * WMLP_FAM + WMLP_B;
    const float*  bp = bbase + fam * BMLP_FAM + BMLP_B;
    int lane = t & 63, wv = t >> 6;
    int r0 = (wv >> 1) * 32, c0 = (wv & 1) * 64;

    const ushort* sb[4]; int lo[4];
    #pragma unroll
    for (int i = 0; i < 4; ++i) {
        int c = wv * 4 + i;
        int isB = c >= 16;
        int cc = c & 15, kb = cc >> 1, hf = cc & 1;
        int row = hf * 64 + lane;
        sb[i] = (isB ? Wb + (size_t)(o0 + row) * H1 : Yin + (size_t)(p0 + row) * H1) + kb * 8;
        lo[i] = (isB ? 8192 : 0) + kb * 1024 + hf * 512;
    }

    f4v acc[2][4];
    #pragma unroll
    for (int m = 0; m < 2; ++m)
        #pragma unroll
        for (int n = 0; n < 4; ++n)
            acc[m][n] = (f4v){0.f, 0.f, 0.f, 0.f};

    const int NKT = H1 / 64;   // 8
    #pragma unroll
    for (int i = 0; i < 4; ++i) gl16(sb[i], &smB[lo[i]]);
    for (int kt = 0; kt < NKT; ++kt) {
        if (kt + 1 < NKT) {
            int nb = ((kt + 1) & 1) << 14;
            int ko = (kt + 1) * 64;
            #pragma unroll
            for (int i = 0; i < 4; ++i) gl16(sb[i] + ko, &smB[nb + lo[i]]);
            asm volatile("s_waitcnt vmcnt(4)" ::: "memory");
        } else {
            asm volatile("s_waitcnt vmcnt(0)" ::: "memory");
        }
        __builtin_amdgcn_sched_barrier(0);
        __builtin_amdgcn_s_barrier();
        __builtin_amdgcn_sched_barrier(0);
        int cb = (kt & 1) << 14;
        #pragma unroll
        for (int ks = 0; ks < 2; ++ks) {
            int kq = (ks * 4 + (lane >> 4)) * 128;
            s8v a[2], b[4];
            #pragma unroll
            for (int m = 0; m < 2; ++m)
                a[m] = *(const s8v*)&smB[cb + (kq + r0 + m * 16 + (lane & 15)) * 8];
            #pragma unroll
            for (int n = 0; n < 4; ++n)
                b[n] = *(const s8v*)&smB[cb + 8192 + (kq + c0 + n * 16 + (lane & 15)) * 8];
            #pragma unroll
            for (int m = 0; m < 2; ++m)
                #pragma unroll
                for (int n = 0; n < 4; ++n)
                    acc[m][n] = __builtin_amdgcn_mfma_f32_16x16x32_bf16(a[m], b[n], acc[m][n], 0, 0, 0);
        }
        __builtin_amdgcn_sched_barrier(0);
        __builtin_amdgcn_s_barrier();
    }

    int cl = lane & 15, rq = lane >> 4;
    if (t < 128) {
        int gs = gs0 + t;
        int n = gs / LO, i = gs - n * LO;
        mvalid[t] = (pep_x[n * LP + 3 + i] != 0) ? 1 : 0;
    }
    #pragma unroll
    for (int m = 0; m < 2; ++m)
        #pragma unroll
        for (int n = 0; n < 4; ++n) {
            int ocr = c0 + n * 16 + cl;
            float bv = bp[o0 + ocr];
            #pragma unroll
            for (int j = 0; j < 4; ++j)
                zbuf[(r0 + m * 16 + rq * 4 + j) * 129 + ocr] = fmaxf(acc[m][n][j] + bv, 0.f);
        }
    __syncthreads();

    // per-column segmented max over samples (21-row periods), 4 quarter-scans
    int col = t & 127, quart = t >> 7;
    int colg = o0 + col;
    int rs = quart * 32;
    int gs = gs0 + rs;
    int n = gs / LO, i = gs - n * LO;
    float cur = -1.f;
    for (int r = rs; r < rs + 32; ++r) {
        if (mvalid[r]) cur = fmaxf(cur, zbuf[r * 129 + col]);
        if (++i == LO) {
            if (cur >= 0.f)
                atomicMax(&poolI[n * (3 * H2) + slot * H2 + colg], __float_as_int(cur));
            cur = -1.f; ++n; i = 0;
        }
    }
    if (cur >= 0.f)
        atomicMax(&poolI[n * (3 * H2) + slot * H2 + colg], __float_as_int(cur));
}

// ---------------- attention head per sample ----------------
__global__ __launch_bounds__(256) void k_poolhead(
    const float* __restrict__ pool,
    const float* __restrict__ w_att1, const float* __restrict__ b_att1,
    const float* __restrict__ w_att2, const float* __restrict__ b_att2,
    const float* __restrict__ w_out, const float* __restrict__ b_out,
    float* __restrict__ a_out, float* __restrict__ s2_out)
{
    int n = blockIdx.x, c = threadIdx.x;
    __shared__ float feat_s[H2];
    __shared__ float red[7][H2];
    __shared__ float sc_s[6];

    float mx[3];
    #pragma unroll
    for (int w = 0; w < 3; ++w)
        mx[w] = pool[(size_t)n * (3 * H2) + w * H2 + c];

    float fv = (mx[0] + mx[1] + mx[2]) * (1.f / 3.f);
    feat_s[c] = fv;
    #pragma unroll
    for (int o = 0; o < 2; ++o)
        #pragma unroll
        for (int w = 0; w < 3; ++w)
            red[o * 3 + w][c] = w_out[o * H2 + c] * mx[w];
    __syncthreads();

    float hacc = 0.f;
    for (int cc = 0; cc < H2; ++cc)
        hacc = fmaf(w_att1[(size_t)c * H2 + cc], feat_s[cc], hacc);
    float h = tanhf(hacc + b_att1[c]);
    red[6][c] = h * w_att2[c];
    __syncthreads();

    for (int s = 128; s > 0; s >>= 1) {
        if (c < s) {
            #pragma unroll
            for (int jj = 0; jj < 7; ++jj) red[jj][c] += red[jj][c + s];
        }
        __syncthreads();
    }
    if (c == 0) a_out[n] = red[6][0] + b_att2[0];
    if (c < 6) {
        float x = red[c][0] + b_out[c / 3];
        sc_s[c] = 1.f / (1.f + expf(-x));
    }
    __syncthreads();
    if (c < 2) {
        float half = 0.5f * (sc_s[c * 3 + 0] + sc_s[c * 3 + 1]);
        s2_out[n * 2 + c] = fmaxf(half, sc_s[c * 3 + 2]);   // inverse==1 path
    }
}

// ---------------- bag segment softmax + weighted sum ----------------
__global__ __launch_bounds__(1024) void k_final(
    const float* __restrict__ a_in, const float* __restrict__ s2_in,
    const int* __restrict__ bags, float* __restrict__ out)
{
    __shared__ float a_s[NS], s0_s[NS], s1_s[NS];
    __shared__ int off_s[33];
    int t = threadIdx.x;
    a_s[t]  = a_in[t];
    s0_s[t] = s2_in[t * 2 + 0];
    s1_s[t] = s2_in[t * 2 + 1];
    if (t == 0) {
        off_s[0] = 0;
        for (int g = 0; g < 32; ++g) off_s[g + 1] = off_s[g] + bags[g];
    }
    __syncthreads();
    if (t < 32) {
        int st = off_s[t], en = off_s[t + 1];
        float mxv = -INFINITY;
        for (int n = st; n < en; ++n) mxv = fmaxf(mxv, a_s[n]);
        float se = 0.f;
        for (int n = st; n < en; ++n) se += expf(a_s[n] - mxv);
        float inv = 1.f / se;
        float o0 = 0.f, o1 = 0.f;
        for (int n = st; n < en; ++n) {
            float w = expf(a_s[n] - mxv) * inv;
            o0 += w * s0_s[n];
            o1 += w * s1_s[n];
        }
        out[t * 2 + 0] = fminf(fmaxf(o0, 0.f), 1.f);
        out[t * 2 + 1] = fminf(fmaxf(o1, 0.f), 1.f);
    }
}

extern "C" void kernel_launch(void* const* d_in, const int* in_sizes, int n_in,
                              void* d_out, int out_size, void* d_ws, size_t ws_size,
                              hipStream_t stream) {
    const int* pep_x = (const int*)d_in[0];
    const int* mhc_x = (const int*)d_in[1];
    const int* bags  = (const int*)d_in[4];

    char* wsb = (char*)d_ws;
    float*  pool   = (float*) (wsb + 0);          // 3,145,728 (stored as int bits)
    int*    poolI  = (int*)   (wsb + 0);
    float*  a_buf  = (float*) (wsb + 3145728);
    float*  s2_buf = (float*) (wsb + 3149824);
    ushort* Wpack  = (ushort*)(wsb + 3158016);
    float*  bpack  = (float*) (wsb + 4042752);
    ushort* Wmlp   = (ushort*)(wsb + 4050432);
    float*  bmlp   = (float*) (wsb + 5885440);
    ushort* Gb     = (ushort*)(wsb + 5891584);
    const size_t XB_B = 8103552;

    size_t fullNeed = XB_B + (size_t)ALLROWS * (1280 + 1024);
    int chunkSlots = (fullNeed <= ws_size) ? 3 : 1;
    int RC = chunkSlots * SLOTROWS;
    ushort* Xb = (ushort*)(wsb + XB_B);                       // RC*640 bf16
    ushort* Yb = (ushort*)((char*)Xb + (size_t)RC * 1280);    // RC*512 bf16

    PrepArgs pa;
    pa.pep_x = pep_x; pa.mhc_x = mhc_x;
    pa.emb_pep = (const float*)d_in[6];
    pa.emb_mhc = (const float*)d_in[7];
    for (int j = 0; j < 3; ++j) {
        pa.cw[0][j]  = (const float*)d_in[8 + 4 * j];
        pa.cb[0][j]  = (const float*)d_in[9 + 4 * j];
        pa.cg[0][j]  = (const float*)d_in[10 + 4 * j];
        pa.cbe[0][j] = (const float*)d_in[11 + 4 * j];
        pa.cw[1][j]  = (const float*)d_in[20 + 4 * j];
        pa.cb[1][j]  = (const float*)d_in[21 + 4 * j];
        pa.cg[1][j]  = (const float*)d_in[22 + 4 * j];
        pa.cbe[1][j] = (const float*)d_in[23 + 4 * j];
    }
    for (int task = 0; task < 4; ++task) {
        int base = 32 + task * 4;
        pa.mw[task]  = (const float*)d_in[base + 0];
        pa.mb[task]  = (const float*)d_in[base + 1];
        pa.mg[task]  = (const float*)d_in[base + 2];
        pa.mbe[task] = (const float*)d_in[base + 3];
    }
    pa.Gb = Gb; pa.Wpack = Wpack; pa.bpack = bpack; pa.Wmlp = Wmlp; pa.bmlp = bmlp;
    pa.poolI = poolI;

    k_prep<<<dim3(NS + 144 + 112 + 96), dim3(256), 0, stream>>>(pa);

    for (int rowBase = 0; rowBase < ALLROWS; rowBase += RC) {
        int nRB = RC / 128;
        k_cmfma<<<dim3(5, nRB), dim3(512), 0, stream>>>(Gb, Wpack, bpack, Xb, rowBase);
        k_mgemmA<<<dim3(H1 / 128, nRB), dim3(512), 0, stream>>>(Xb, Wmlp, bmlp, Yb, rowBase);
        k_mgemmB<<<dim3(H2 / 128, nRB), dim3(512), 0, stream>>>(Yb, Wmlp, bmlp, pep_x, poolI, rowBase);
    }

    k_poolhead<<<dim3(NS), dim3(256), 0, stream>>>(
        pool,
        (const float*)d_in[48], (const float*)d_in[49], (const float*)d_in[50], (const float*)d_in[51],
        (const float*)d_in[52], (const float*)d_in[53],
        a_buf, s2_buf);

    k_final<<<dim3(1), dim3(1024), 0, stream>>>(a_buf, s2_buf, bags, (float*)d_out);
}

// Round 18
// 189.097 us; speedup vs baseline: 1.1382x; 1.1382x over previous
//
#include <hip/hip_runtime.h>
#include <hip/hip_bf16.h>
#include <math.h>

#define NS   1024
#define LP   27
#define MMH  34
#define EE   16
#define LO   21
#define CT   640
#define H1   512
#define H2   256
#define LPAD 40
#define GROW (LP*LPAD)      // 1080 bf16 els per sample
#define SLOTROWS (NS*LO)    // 21504
#define ALLROWS  (3*SLOTROWS)

typedef __attribute__((ext_vector_type(8))) short  s8v;
typedef __attribute__((ext_vector_type(4))) float  f4v;

// packed conv-weight geometry: col = k*40 + m, Kcp = K*40 padded to mult-32
#define PK2_SLOT 147456     // 128*128 + 256*224 + 256*288
#define PK2_J0   0
#define PK2_J1   16384
#define PK2_J2   73728
// MLP pack offsets
#define WMLP_FAM 458752     // 512*640 + 256*512
#define WMLP_B   327680     // 512*640
#define BMLP_FAM 768
#define BMLP_B   512

__device__ __forceinline__ ushort f2b(float v) {
    __hip_bfloat16 hb = __float2bfloat16(v);
    return *reinterpret_cast<ushort*>(&hb);
}

__device__ __forceinline__ float pe_val(int pos, int e) {
    int j = e >> 1;
    float div = expf(-1.1512925464970229f * (float)j);  // 10000^(-j/8)
    float ang = (float)pos * div;
    return (e & 1) ? cosf(ang) : sinf(ang);
}

// XCD-aware bijective swizzle of the flat workgroup id (T1; requires nwg%8==0)
__device__ __forceinline__ int xcd_swz() {
    int fid = blockIdx.y * gridDim.x + blockIdx.x;
    int nwg = gridDim.x * gridDim.y;
    int cpx = nwg >> 3;
    return (fid & 7) * cpx + (fid >> 3);
}

// ---------------- fused prep: embG | conv pack | mlp pack | pool zero ----------------
struct PrepArgs {
    const int* pep_x; const int* mhc_x;
    const float* emb_pep; const float* emb_mhc;
    const float* cw[2][3]; const float* cb[2][3]; const float* cg[2][3]; const float* cbe[2][3];
    const float* mw[4]; const float* mb[4]; const float* mg[4]; const float* mbe[4];
    ushort* Gb; ushort* Wpack; float* bpack; ushort* Wmlp; float* bmlp; int* poolI;
};

__global__ __launch_bounds__(256) void k_prep(PrepArgs A) {
    int b = blockIdx.x, t = threadIdx.x;
    float rs = rsqrtf(1.0f + 1e-5f);
    if (b < NS) {
        __shared__ float ps[LP * 17];
        __shared__ float ms[MMH * 17];
        int n = b;
        for (int idx = t; idx < LP * EE; idx += 256) {
            int l = idx >> 4, e = idx & 15;
            float v = A.emb_pep[A.pep_x[n * LP + l] * EE + e];
            if (l >= 3 && l < 24) v += pe_val(l - 3, e);
            ps[l * 17 + e] = v;
        }
        for (int idx = t; idx < MMH * EE; idx += 256) {
            int m = idx >> 4, e = idx & 15;
            ms[m * 17 + e] = A.emb_mhc[A.mhc_x[n * MMH + m] * EE + e] + pe_val(m, e);
        }
        __syncthreads();
        for (int idx = t; idx < GROW; idx += 256) {
            int l = idx / LPAD, m = idx - l * LPAD;
            float s = 0.f;
            if (m < MMH) {
                #pragma unroll
                for (int e = 0; e < EE; ++e) s = fmaf(ps[l * 17 + e], ms[m * 17 + e], s);
            }
            A.Gb[(size_t)n * GROW + idx] = f2b(s);
        }
        if (n == 0 && t < 64) A.Gb[(size_t)NS * GROW + t] = 0;
    } else if (b < NS + 144) {
        const int KS_[3]  = {3, 5, 7};
        const int KCP_[3] = {128, 224, 288};
        const int NC_[3]  = {128, 256, 256};
        const int pkoff[3] = {PK2_J0, PK2_J1, PK2_J2};
        const int bpoff[3] = {0, 128, 384};
        int lin = b - NS;
        int s = lin / 48, rem = lin - s * 48, j = rem >> 4, z = rem & 15;
        int K = KS_[j], Kcp = KCP_[j], nc = NC_[j];
        int fam = (s == 0) ? 0 : 1;
        const float* w  = A.cw[fam][j];
        const float* g  = A.cg[fam][j];
        ushort* Wp = A.Wpack + s * PK2_SLOT + pkoff[j];
        int tot = nc * Kcp;
        for (int idx = z * 256 + t; idx < tot; idx += 16 * 256) {
            int c = idx / Kcp, col = idx - c * Kcp;
            int k = col / LPAD, m = col - k * LPAD;
            float v = 0.f;
            if (k < K && m < MMH) {
                int kk = (s == 2) ? (K - 1 - k) : k;
                v = w[((size_t)c * K + kk) * MMH + m] * (g[c] * rs);
            }
            Wp[idx] = f2b(v);
        }
        if (z == 0) {
            const float* bb = A.cb[fam][j];
            const float* be = A.cbe[fam][j];
            float* bp = A.bpack + s * CT + bpoff[j];
            for (int c = t; c < nc; c += 256)
                bp[c] = bb[c] * (g[c] * rs) + be[c];
        }
    } else if (b < NS + 144 + 112) {
        int lin = b - NS - 144;
        int task, rel, nb;
        if (lin < 40)      { task = 0; rel = lin;      nb = 40; }
        else if (lin < 56) { task = 1; rel = lin - 40; nb = 16; }
        else if (lin < 96) { task = 2; rel = lin - 56; nb = 40; }
        else               { task = 3; rel = lin - 96; nb = 16; }
        int fam = task >> 1, stage = task & 1;
        int Co = stage ? H2 : H1;
        int Ci = stage ? H1 : CT;
        const float* w  = A.mw[task];
        const float* g  = A.mg[task];
        ushort* Wb = A.Wmlp + fam * WMLP_FAM + stage * WMLP_B;
        int tot = Co * Ci;
        for (int idx = rel * 256 + t; idx < tot; idx += nb * 256) {
            int o = idx / Ci;
            Wb[idx] = f2b(w[idx] * (g[o] * rs));
        }
        if (rel == 0) {
            const float* bb = A.mb[task];
            const float* be = A.mbe[task];
            float* bp = A.bmlp + fam * BMLP_FAM + stage * BMLP_B;
            for (int o = t; o < Co; o += 256)
                bp[o] = bb[o] * (g[o] * rs) + be[o];
        }
    } else {
        int base = (b - NS - 144 - 112) * 8192;
        #pragma unroll
        for (int q = 0; q < 32; ++q)
            A.poolI[base + q * 256 + t] = 0;
    }
}

// ---------------- conv as bf16 MFMA GEMM, 8 waves, XCD-swizzled ----------------
__global__ __launch_bounds__(512) void k_cmfma(
    const ushort* __restrict__ Gb, const ushort* __restrict__ Wpack,
    const float* __restrict__ bpack, ushort* __restrict__ Xb, int rowBase)
{
    const int kcpm[5] = {128, 224, 224, 288, 288};
    const int offm[5] = {2, 1, 1, 0, 0};
    const int o0m[5]  = {0, 0, 128, 0, 128};
    const int c0m[5]  = {0, 128, 128, 384, 384};
    const int wofm[5] = {PK2_J0, PK2_J1, PK2_J1, PK2_J2, PK2_J2};

    __shared__ ushort smC[17408];           // staging 10240 | epi 17408 (aliased)
    ushort* Al = smC;
    ushort* Bl = smC + 5120;
    int wg = xcd_swz();
    int y = wg % 5, rtile = wg / 5;
    int Kcp = kcpm[y], off = offm[y], o0 = o0m[y];
    int c0X = c0m[y] + o0;
    int r0g = rowBase + rtile * 128;
    int slot = r0g / SLOTROWS;
    const ushort* Wt = Wpack + slot * PK2_SLOT + wofm[y] + (size_t)o0 * Kcp;
    const float*  bp = bpack + slot * CT;
    int p0 = rtile * 128;

    int t = threadIdx.x, lane = t & 63, wv = t >> 6;
    int r0 = (wv >> 1) * 32, c0w = (wv & 1) * 64;

    int row_a = t >> 2, seg = t & 3;          // 512 threads: 128 rows x 4 segs
    int rg0 = r0g + row_a;
    int rr0 = rg0 - slot * SLOTROWS;
    size_t wb0 = (size_t)(rr0 / LO) * GROW + (off + rr0 % LO) * LPAD;

    f4v acc[2][4];
    #pragma unroll
    for (int m = 0; m < 2; ++m)
        #pragma unroll
        for (int n = 0; n < 4; ++n)
            acc[m][n] = (f4v){0.f, 0.f, 0.f, 0.f};

    int nkt = Kcp >> 5;
    for (int kt = 0; kt < nkt; ++kt) {
        int k0 = kt << 5;
        __syncthreads();
        *(s8v*)&Al[row_a * 40 + seg * 8] = *(const s8v*)&Gb[wb0 + k0 + seg * 8];
        *(s8v*)&Bl[row_a * 40 + seg * 8] = *(const s8v*)&Wt[(size_t)row_a * Kcp + k0 + seg * 8];
        __syncthreads();
        s8v a[2], b[4];
        #pragma unroll
        for (int m = 0; m < 2; ++m)
            a[m] = *(const s8v*)&Al[(r0 + m * 16 + (lane & 15)) * 40 + (lane >> 4) * 8];
        #pragma unroll
        for (int n = 0; n < 4; ++n)
            b[n] = *(const s8v*)&Bl[(c0w + n * 16 + (lane & 15)) * 40 + (lane >> 4) * 8];
        #pragma unroll
        for (int m = 0; m < 2; ++m)
            #pragma unroll
            for (int n = 0; n < 4; ++n)
                acc[m][n] = __builtin_amdgcn_mfma_f32_16x16x32_bf16(a[m], b[n], acc[m][n], 0, 0, 0);
    }

    int cl = lane & 15, rq = lane >> 4;
    __syncthreads();
    #pragma unroll
    for (int m = 0; m < 2; ++m)
        #pragma unroll
        for (int n = 0; n < 4; ++n) {
            int ocr = c0w + n * 16 + cl;
            float bv = bp[c0X + ocr];
            #pragma unroll
            for (int j = 0; j < 4; ++j)
                smC[(r0 + m * 16 + rq * 4 + j) * 136 + ocr] = f2b(fmaxf(acc[m][n][j] + bv, 0.f));
        }
    __syncthreads();
    int ci = t & 15;
    #pragma unroll
    for (int it = 0; it < 4; ++it) {
        int row = (t >> 4) + it * 32;
        *(s8v*)&Xb[(size_t)(p0 + row) * CT + c0X + ci * 8] = *(const s8v*)&smC[row * 136 + ci * 8];
    }
}

// ---------------- MLP stage A: bf16 MFMA GEMM, BK=64, 8 waves, XCD-swizzled ----------------
__global__ __launch_bounds__(512) void k_mgemmA(
    const ushort* __restrict__ Xin,
    const ushort* __restrict__ Wbase, const float* __restrict__ bbase,
    ushort* __restrict__ Yb, int rowBase)
{
    __shared__ ushort smA[18432];          // staging 2*9216 | epi 17408 (aliased)
    ushort* Al = smA;
    ushort* Bl = smA + 9216;
    int t = threadIdx.x;
    int wg = xcd_swz();
    int o0 = (wg & 3) * 128;
    int p0 = (wg >> 2) * 128;
    int g0 = rowBase + p0;
    int fam = (g0 < SLOTROWS) ? 0 : 1;
    const ushort* Wb = Wbase + (size_t)fam * WMLP_FAM;
    const float*  bp = bbase + fam * BMLP_FAM;
    int lane = t & 63, wv = t >> 6;
    int r0 = (wv >> 1) * 32, c0 = (wv & 1) * 64;

    f4v acc[2][4];
    #pragma unroll
    for (int m = 0; m < 2; ++m)
        #pragma unroll
        for (int n = 0; n < 4; ++n)
            acc[m][n] = (f4v){0.f, 0.f, 0.f, 0.f};

    for (int kt = 0; kt < CT / 64; ++kt) {
        int k0 = kt << 6;
        __syncthreads();
        #pragma unroll
        for (int it = 0; it < 2; ++it) {
            int idx = t + it * 512;
            int row = idx >> 3, sg = idx & 7;
            *(s8v*)&Al[row * 72 + sg * 8] = *(const s8v*)&Xin[(size_t)(p0 + row) * CT + k0 + sg * 8];
            *(s8v*)&Bl[row * 72 + sg * 8] = *(const s8v*)&Wb[(size_t)(o0 + row) * CT + k0 + sg * 8];
        }
        __syncthreads();
        #pragma unroll
        for (int ks = 0; ks < 2; ++ks) {
            int kc = ks * 32 + (lane >> 4) * 8;
            s8v a[2], b[4];
            #pragma unroll
            for (int m = 0; m < 2; ++m)
                a[m] = *(const s8v*)&Al[(r0 + m * 16 + (lane & 15)) * 72 + kc];
            #pragma unroll
            for (int n = 0; n < 4; ++n)
                b[n] = *(const s8v*)&Bl[(c0 + n * 16 + (lane & 15)) * 72 + kc];
            #pragma unroll
            for (int m = 0; m < 2; ++m)
                #pragma unroll
                for (int n = 0; n < 4; ++n)
                    acc[m][n] = __builtin_amdgcn_mfma_f32_16x16x32_bf16(a[m], b[n], acc[m][n], 0, 0, 0);
        }
    }

    int cl = lane & 15, rq = lane >> 4;
    __syncthreads();
    #pragma unroll
    for (int m = 0; m < 2; ++m)
        #pragma unroll
        for (int n = 0; n < 4; ++n) {
            int ocr = c0 + n * 16 + cl;
            float bv = bp[o0 + ocr];
            #pragma unroll
            for (int j = 0; j < 4; ++j)
                smA[(r0 + m * 16 + rq * 4 + j) * 136 + ocr] = f2b(fmaxf(acc[m][n][j] + bv, 0.f));
        }
    __syncthreads();
    int ci = t & 15;
    #pragma unroll
    for (int it = 0; it < 4; ++it) {
        int row = (t >> 4) + it * 32;
        *(s8v*)&Yb[(size_t)(p0 + row) * H1 + o0 + ci * 8] = *(const s8v*)&smA[row * 136 + ci * 8];
    }
}

// ---------------- MLP stage B fused with masked max-pool, 8 waves, XCD-swizzled ----------------
__global__ __launch_bounds__(512) void k_mgemmB(
    const ushort* __restrict__ Yin,
    const ushort* __restrict__ Wbase, const float* __restrict__ bbase,
    const int* __restrict__ pep_x, int* __restrict__ poolI, int rowBase)
{
    __shared__ float zbuf[128 * 129];      // 66048 B; staging aliased at front
    __shared__ int mvalid[128];
    ushort* Al = (ushort*)zbuf;
    ushort* Bl = Al + 9216;
    int t = threadIdx.x;
    int wg = xcd_swz();
    int o0 = (wg & 1) * 128;
    int p0 = (wg >> 1) * 128;
    int g0 = rowBase + p0;
    int slot = g0 / SLOTROWS;
    int gs0 = g0 - slot * SLOTROWS;
    int fam = (slot == 0) ? 0 : 1;
    const ushort* Wb = Wbase + (size_t)fam * WMLP_FAM + WMLP_B;
    const float*  bp = bbase + fam * BMLP_FAM + BMLP_B;
    int lane = t & 63, wv = t >> 6;
    int r0 = (wv >> 1) * 32, c0 = (wv & 1) * 64;

    f4v acc[2][4];
    #pragma unroll
    for (int m = 0; m < 2; ++m)
        #pragma unroll
        for (int n = 0; n < 4; ++n)
            acc[m][n] = (f4v){0.f, 0.f, 0.f, 0.f};

    for (int kt = 0; kt < H1 / 64; ++kt) {
        int k0 = kt << 6;
        __syncthreads();
        #pragma unroll
        for (int it = 0; it < 2; ++it) {
            int idx = t + it * 512;
            int row = idx >> 3, sg = idx & 7;
            *(s8v*)&Al[row * 72 + sg * 8] = *(const s8v*)&Yin[(size_t)(p0 + row) * H1 + k0 + sg * 8];
            *(s8v*)&Bl[row * 72 + sg * 8] = *(const s8v*)&Wb[(size_t)(o0 + row) * H1 + k0 + sg * 8];
        }
        __syncthreads();
        #pragma unroll
        for (int ks = 0; ks < 2; ++ks) {
            int kc = ks * 32 + (lane >> 4) * 8;
            s8v a[2], b[4];
            #pragma unroll
            for (int m = 0; m < 2; ++m)
                a[m] = *(const s8v*)&Al[(r0 + m * 16 + (lane & 15)) * 72 + kc];
            #pragma unroll
            for (int n = 0; n < 4; ++n)
                b[n] = *(const s8v*)&Bl[(c0 + n * 16 + (lane & 15)) * 72 + kc];
            #pragma unroll
            for (int m = 0; m < 2; ++m)
                #pragma unroll
                for (int n = 0; n < 4; ++n)
                    acc[m][n] = __builtin_amdgcn_mfma_f32_16x16x32_bf16(a[m], b[n], acc[m][n], 0, 0, 0);
        }
    }

    int cl = lane & 15, rq = lane >> 4;
    __syncthreads();
    if (t < 128) {
        int gs = gs0 + t;
        int n = gs / LO, i = gs - n * LO;
        mvalid[t] = (pep_x[n * LP + 3 + i] != 0) ? 1 : 0;
    }
    #pragma unroll
    for (int m = 0; m < 2; ++m)
        #pragma unroll
        for (int n = 0; n < 4; ++n) {
            int ocr = c0 + n * 16 + cl;
            float bv = bp[o0 + ocr];
            #pragma unroll
            for (int j = 0; j < 4; ++j)
                zbuf[(r0 + m * 16 + rq * 4 + j) * 129 + ocr] = fmaxf(acc[m][n][j] + bv, 0.f);
        }
    __syncthreads();

    // per-column segmented max over samples (21-row periods), 4 quarter-scans
    int col = t & 127, quart = t >> 7;
    int colg = o0 + col;
    int rs = quart * 32;
    int gs = gs0 + rs;
    int n = gs / LO, i = gs - n * LO;
    float cur = -1.f;
    for (int r = rs; r < rs + 32; ++r) {
        if (mvalid[r]) cur = fmaxf(cur, zbuf[r * 129 + col]);
        if (++i == LO) {
            if (cur >= 0.f)
                atomicMax(&poolI[n * (3 * H2) + slot * H2 + colg], __float_as_int(cur));
            cur = -1.f; ++n; i = 0;
        }
    }
    if (cur >= 0.f)
        atomicMax(&poolI[n * (3 * H2) + slot * H2 + colg], __float_as_int(cur));
}

// ---------------- attention head per sample ----------------
__global__ __launch_bounds__(256) void k_poolhead(
    const float* __restrict__ pool,
    const float* __restrict__ w_att1, const float* __restrict__ b_att1,
    const float* __restrict__ w_att2, const float* __restrict__ b_att2,
    const float* __restrict__ w_out, const float* __restrict__ b_out,
    float* __restrict__ a_out, float* __restrict__ s2_out)
{
    int n = blockIdx.x, c = threadIdx.x;
    __shared__ float feat_s[H2];
    __shared__ float red[7][H2];
    __shared__ float sc_s[6];

    float mx[3];
    #pragma unroll
    for (int w = 0; w < 3; ++w)
        mx[w] = pool[(size_t)n * (3 * H2) + w * H2 + c];

    float fv = (mx[0] + mx[1] + mx[2]) * (1.f / 3.f);
    feat_s[c] = fv;
    #pragma unroll
    for (int o = 0; o < 2; ++o)
        #pragma unroll
        for (int w = 0; w < 3; ++w)
            red[o * 3 + w][c] = w_out[o * H2 + c] * mx[w];
    __syncthreads();

    float hacc = 0.f;
    for (int cc = 0; cc < H2; ++cc)
        hacc = fmaf(w_att1[(size_t)c * H2 + cc], feat_s[cc], hacc);
    float h = tanhf(hacc + b_att1[c]);
    red[6][c] = h * w_att2[c];
    __syncthreads();

    for (int s = 128; s > 0; s >>= 1) {
        if (c < s) {
            #pragma unroll
            for (int jj = 0; jj < 7; ++jj) red[jj][c] += red[jj][c + s];
        }
        __syncthreads();
    }
    if (c == 0) a_out[n] = red[6][0] + b_att2[0];
    if (c < 6) {
        float x = red[c][0] + b_out[c / 3];
        sc_s[c] = 1.f / (1.f + expf(-x));
    }
    __syncthreads();
    if (c < 2) {
        float half = 0.5f * (sc_s[c * 3 + 0] + sc_s[c * 3 + 1]);
        s2_out[n * 2 + c] = fmaxf(half, sc_s[c * 3 + 2]);   // inverse==1 path
    }
}

// ---------------- bag segment softmax + weighted sum ----------------
__global__ __launch_bounds__(1024) void k_final(
    const float* __restrict__ a_in, const float* __restrict__ s2_in,
    const int* __restrict__ bags, float* __restrict__ out)
{
    __shared__ float a_s[NS], s0_s[NS], s1_s[NS];
    __shared__ int off_s[33];
    int t = threadIdx.x;
    a_s[t]  = a_in[t];
    s0_s[t] = s2_in[t * 2 + 0];
    s1_s[t] = s2_in[t * 2 + 1];
    if (t == 0) {
        off_s[0] = 0;
        for (int g = 0; g < 32; ++g) off_s[g + 1] = off_s[g] + bags[g];
    }
    __syncthreads();
    if (t < 32) {
        int st = off_s[t], en = off_s[t + 1];
        float mxv = -INFINITY;
        for (int n = st; n < en; ++n) mxv = fmaxf(mxv, a_s[n]);
        float se = 0.f;
        for (int n = st; n < en; ++n) se += expf(a_s[n] - mxv);
        float inv = 1.f / se;
        float o0 = 0.f, o1 = 0.f;
        for (int n = st; n < en; ++n) {
            float w = expf(a_s[n] - mxv) * inv;
            o0 += w * s0_s[n];
            o1 += w * s1_s[n];
        }
        out[t * 2 + 0] = fminf(fmaxf(o0, 0.f), 1.f);
        out[t * 2 + 1] = fminf(fmaxf(o1, 0.f), 1.f);
    }
}

extern "C" void kernel_launch(void* const* d_in, const int* in_sizes, int n_in,
                              void* d_out, int out_size, void* d_ws, size_t ws_size,
                              hipStream_t stream) {
    const int* pep_x = (const int*)d_in[0];
    const int* mhc_x = (const int*)d_in[1];
    const int* bags  = (const int*)d_in[4];

    char* wsb = (char*)d_ws;
    float*  pool   = (float*) (wsb + 0);          // 3,145,728 (stored as int bits)
    int*    poolI  = (int*)   (wsb + 0);
    float*  a_buf  = (float*) (wsb + 3145728);
    float*  s2_buf = (float*) (wsb + 3149824);
    ushort* Wpack  = (ushort*)(wsb + 3158016);
    float*  bpack  = (float*) (wsb + 4042752);
    ushort* Wmlp   = (ushort*)(wsb + 4050432);
    float*  bmlp   = (float*) (wsb + 5885440);
    ushort* Gb     = (ushort*)(wsb + 5891584);
    const size_t XB_B = 8103552;

    size_t fullNeed = XB_B + (size_t)ALLROWS * (1280 + 1024);
    int chunkSlots = (fullNeed <= ws_size) ? 3 : 1;
    int RC = chunkSlots * SLOTROWS;
    ushort* Xb = (ushort*)(wsb + XB_B);                       // RC*640 bf16
    ushort* Yb = (ushort*)((char*)Xb + (size_t)RC * 1280);    // RC*512 bf16

    PrepArgs pa;
    pa.pep_x = pep_x; pa.mhc_x = mhc_x;
    pa.emb_pep = (const float*)d_in[6];
    pa.emb_mhc = (const float*)d_in[7];
    for (int j = 0; j < 3; ++j) {
        pa.cw[0][j]  = (const float*)d_in[8 + 4 * j];
        pa.cb[0][j]  = (const float*)d_in[9 + 4 * j];
        pa.cg[0][j]  = (const float*)d_in[10 + 4 * j];
        pa.cbe[0][j] = (const float*)d_in[11 + 4 * j];
        pa.cw[1][j]  = (const float*)d_in[20 + 4 * j];
        pa.cb[1][j]  = (const float*)d_in[21 + 4 * j];
        pa.cg[1][j]  = (const float*)d_in[22 + 4 * j];
        pa.cbe[1][j] = (const float*)d_in[23 + 4 * j];
    }
    for (int task = 0; task < 4; ++task) {
        int base = 32 + task * 4;
        pa.mw[task]  = (const float*)d_in[base + 0];
        pa.mb[task]  = (const float*)d_in[base + 1];
        pa.mg[task]  = (const float*)d_in[base + 2];
        pa.mbe[task] = (const float*)d_in[base + 3];
    }
    pa.Gb = Gb; pa.Wpack = Wpack; pa.bpack = bpack; pa.Wmlp = Wmlp; pa.bmlp = bmlp;
    pa.poolI = poolI;

    k_prep<<<dim3(NS + 144 + 112 + 96), dim3(256), 0, stream>>>(pa);

    for (int rowBase = 0; rowBase < ALLROWS; rowBase += RC) {
        int nRB = RC / 128;
        k_cmfma<<<dim3(5, nRB), dim3(512), 0, stream>>>(Gb, Wpack, bpack, Xb, rowBase);
        k_mgemmA<<<dim3(H1 / 128, nRB), dim3(512), 0, stream>>>(Xb, Wmlp, bmlp, Yb, rowBase);
        k_mgemmB<<<dim3(H2 / 128, nRB), dim3(512), 0, stream>>>(Yb, Wmlp, bmlp, pep_x, poolI, rowBase);
    }

    k_poolhead<<<dim3(NS), dim3(256), 0, stream>>>(
        pool,
        (const float*)d_in[48], (const float*)d_in[49], (const float*)d_in[50], (const float*)d_in[51],
        (const float*)d_in[52], (const float*)d_in[53],
        a_buf, s2_buf);

    k_final<<<dim3(1), dim3(1024), 0, stream>>>(a_buf, s2_buf, bags, (float*)d_out);
}